// Round 4
// baseline (381.452 us; speedup 1.0000x reference)
//
#include <hip/hip_runtime.h>
#include <hip/hip_cooperative_groups.h>
#include <math.h>

namespace cg = cooperative_groups;

// Capsule dynamic routing, MI355X. Round 4: cooperative single-kernel with
// slim LDS (26 KB, Cs/Gp lifetime-overlapped) + runtime fallback to a
// deterministic no-atomic 6-dispatch chain if the coop launch is rejected.
//   logits[b,j,n] = u[b,n,:] . V[b,j,:],  V[b,j,k] = sum_d W[k,jd]*o[b,j,d]
//   o[b,j,d]      = sum_k G[b,j,k]*W[k,jd], G[b,j,k] = sum_n c[b,j,n]*u[b,n,k]
// iter0: c uniform 0.1 -> o0 = 0.1*(colsum u)@W.

#define BATCH 64
#define NN    2048
#define KD    128
#define JCAP  10
#define DCAP  16
#define JDIM  160
#define EPSQ  1e-7f
#define NBLK  512   // 64 batches x 8 tiles of 256 rows
#define TPB   256

// ======================= cooperative single kernel =======================
__global__ __launch_bounds__(TPB, 2) void k_caps(const float* __restrict__ u,
                                                 const float* __restrict__ W,
                                                 float* __restrict__ out,
                                                 float* __restrict__ ws) {
  cg::grid_group grid = cg::this_grid();
  const int g    = blockIdx.x;
  const int t    = threadIdx.x;
  const int b    = g >> 3;
  const int tile = g & 7;
  const int r0   = tile * 256;

  float* S  = ws;                  //  8192 floats
  float* G1 = ws + 8192;           // 81920 floats
  float* O2 = ws + 8192 + 81920;   // 10240 floats

  __shared__ __align__(16) float V_s[JCAP * KD];   // 5 KB
  __shared__ __align__(16) float Big[4 * JCAP * KD]; // 20 KB: Gp[4][10][128];
                                                     // also Cs[10][260]; also
                                                     // float4 red[256]
  __shared__ float o_s[JDIM];
  __shared__ float sc[JCAP];
#define CS(j, r)     Big[(j) * 260 + (r)]
#define GP(w, j, k)  Big[(w) * (JCAP * KD) + (j) * KD + (k)]

  // ---- stage 0: zero S, G1, O2 (ws is poisoned 0xAA each call) ----
  {
    const int idx = g * TPB + t;
    if (idx < 8192 + 81920 + 10240) ws[idx] = 0.f;
  }
  grid.sync();

  // ---- stage A: S[b][k] = sum_n u[b][n][k] ----
  {
    const int k4 = (t & 31) * 4;
    const int rg = t >> 5;
    const float* p = u + ((size_t)(b * NN) + r0 + rg * 32) * KD + k4;
    float4 a = make_float4(0.f, 0.f, 0.f, 0.f);
#pragma unroll 4
    for (int r = 0; r < 32; ++r) {
      float4 w = *(const float4*)(p + (size_t)r * KD);
      a.x += w.x; a.y += w.y; a.z += w.z; a.w += w.w;
    }
    float4* red = (float4*)Big;
    red[t] = a;
    __syncthreads();
    if (t < 32) {
      float4 s4 = red[t];
#pragma unroll
      for (int rg2 = 1; rg2 < 8; ++rg2) {
        float4 w = red[rg2 * 32 + t];
        s4.x += w.x; s4.y += w.y; s4.z += w.z; s4.w += w.w;
      }
      atomicAdd(&S[b * KD + t * 4 + 0], s4.x);
      atomicAdd(&S[b * KD + t * 4 + 1], s4.y);
      atomicAdd(&S[b * KD + t * 4 + 2], s4.z);
      atomicAdd(&S[b * KD + t * 4 + 3], s4.w);
    }
  }
  grid.sync();

  for (int pass = 0; pass < 2; ++pass) {
    // makeV (per-block redundant): o = scale * Gin @ W ; V = o @ W^T-slices
    {
      if (t < JDIM) {
        const int j = t >> 4;
        const float* gs = pass == 0 ? (S + b * KD)
                                    : (G1 + (size_t)(b * JCAP + j) * KD);
        float acc = 0.f;
#pragma unroll 4
        for (int k = 0; k < KD; ++k) acc += gs[k] * W[k * JDIM + t];
        o_s[t] = pass == 0 ? acc * 0.1f : acc;
      }
      __syncthreads();
      const int k = t & 127, gg = t >> 7;
#pragma unroll
      for (int i = 0; i < 5; ++i) {
        const int j = gg * 5 + i;
        const float* wp = W + k * JDIM + j * DCAP;
        float acc = 0.f;
#pragma unroll
        for (int d = 0; d < DCAP; ++d) acc += wp[d] * o_s[j * DCAP + d];
        V_s[j * KD + k] = acc;
      }
      __syncthreads();
    }

    // phase 1: logits + softmax (thread = row), write c into CS region
    {
      const float* up = u + (size_t)(b * NN + r0 + t) * KD;
      float acc[JCAP];
#pragma unroll
      for (int j = 0; j < JCAP; ++j) acc[j] = 0.f;
      for (int kc = 0; kc < KD; kc += 8) {
        float4 xa = *(const float4*)(up + kc);
        float4 xb = *(const float4*)(up + kc + 4);
#pragma unroll
        for (int j = 0; j < JCAP; ++j) {
          float4 v0 = *(const float4*)(V_s + j * KD + kc);
          float4 v1 = *(const float4*)(V_s + j * KD + kc + 4);
          acc[j] += xa.x * v0.x + xa.y * v0.y + xa.z * v0.z + xa.w * v0.w
                  + xb.x * v1.x + xb.y * v1.y + xb.z * v1.z + xb.w * v1.w;
        }
      }
      float m = acc[0];
#pragma unroll
      for (int j = 1; j < JCAP; ++j) m = fmaxf(m, acc[j]);
      float s = 0.f;
#pragma unroll
      for (int j = 0; j < JCAP; ++j) { acc[j] = __expf(acc[j] - m); s += acc[j]; }
      const float inv = 1.f / s;
#pragma unroll
      for (int j = 0; j < JCAP; ++j) CS(j, t) = acc[j] * inv;
    }
    __syncthreads();

    // phase 2: G partials in registers (wave = 64 rows, lane = 2 k-cols)
    {
      const int wave = t >> 6, lane = t & 63;
      const int rw = wave * 64;
      float g0[JCAP], g1[JCAP];
#pragma unroll
      for (int j = 0; j < JCAP; ++j) { g0[j] = 0.f; g1[j] = 0.f; }
      const float* ub = u + (size_t)(b * NN + r0 + rw) * KD + 2 * lane;
      for (int rc = 0; rc < 64; rc += 4) {
        float ua[4], uc[4];
#pragma unroll
        for (int q = 0; q < 4; ++q) {
          float2 w = *(const float2*)(ub + (size_t)(rc + q) * KD);
          ua[q] = w.x; uc[q] = w.y;
        }
#pragma unroll
        for (int j = 0; j < JCAP; ++j) {
          float4 c4 = *(const float4*)&CS(j, rw + rc);
          g0[j] += c4.x * ua[0] + c4.y * ua[1] + c4.z * ua[2] + c4.w * ua[3];
          g1[j] += c4.x * uc[0] + c4.y * uc[1] + c4.z * uc[2] + c4.w * uc[3];
        }
      }
      __syncthreads();   // all CS reads done before Gp overwrites the buffer
#pragma unroll
      for (int j = 0; j < JCAP; ++j)
        *(float2*)&GP(wave, j, 2 * lane) = make_float2(g0[j], g1[j]);
    }
    __syncthreads();

    if (pass == 0) {
      // reduce 4 waves -> atomicAdd into G1
      for (int i = t; i < JCAP * KD; i += TPB) {
        float v = GP(0, 0, i) + GP(1, 0, i) + GP(2, 0, i) + GP(3, 0, i);
        atomicAdd(&G1[(size_t)b * JCAP * KD + i], v);
      }
      grid.sync();
    } else {
      // reduce 4 waves into GP(0), fold through W into O2 partials
      for (int i = t; i < JCAP * KD; i += TPB)
        GP(0, 0, i) = GP(0, 0, i) + GP(1, 0, i) + GP(2, 0, i) + GP(3, 0, i);
      __syncthreads();
      if (t < JDIM) {
        const int j = t >> 4;
        float acc = 0.f;
#pragma unroll 4
        for (int k = 0; k < KD; ++k) acc += GP(0, j, k) * W[k * JDIM + t];
        atomicAdd(&O2[b * JDIM + t], acc);
      }
      grid.sync();
    }
  }

  // ---- stage F: squash + store (one block per batch) ----
  if (tile == 0) {
    if (t < JDIM) o_s[t] = O2[b * JDIM + t];
    __syncthreads();
    if (t < JCAP) {
      float s2 = 0.f;
#pragma unroll
      for (int d = 0; d < DCAP; ++d) { float x = o_s[t * DCAP + d]; s2 += x * x; }
      sc[t] = s2 / ((1.f + s2) * sqrtf(s2 + EPSQ));
    }
    __syncthreads();
    if (t < JDIM) out[b * JDIM + t] = o_s[t] * sc[t >> 4];
  }
#undef CS
#undef GP
}

// ================== fallback chain (no atomics, no memset) ==================
// ws layout (floats): Sp[64][8][128] @0 ; V[64][10][128] @65536 ;
// Gp1[64][8][10][128] @147456 ; O2p[64][8][160] @802816
#define WS_SP   0
#define WS_V    65536
#define WS_GP1  147456
#define WS_O2P  802816

__global__ __launch_bounds__(TPB) void f_colsum(const float* __restrict__ u,
                                                float* __restrict__ Sp) {
  const int b = blockIdx.y, tile = blockIdx.x, t = threadIdx.x;
  const int k4 = (t & 31) * 4, rg = t >> 5;
  __shared__ float4 red[256];
  const float* p = u + ((size_t)(b * NN) + tile * 256 + rg * 32) * KD + k4;
  float4 a = make_float4(0.f, 0.f, 0.f, 0.f);
#pragma unroll 4
  for (int r = 0; r < 32; ++r) {
    float4 w = *(const float4*)(p + (size_t)r * KD);
    a.x += w.x; a.y += w.y; a.z += w.z; a.w += w.w;
  }
  red[t] = a;
  __syncthreads();
  if (t < 32) {
    float4 s4 = red[t];
#pragma unroll
    for (int rg2 = 1; rg2 < 8; ++rg2) {
      float4 w = red[rg2 * 32 + t];
      s4.x += w.x; s4.y += w.y; s4.z += w.z; s4.w += w.w;
    }
    *(float4*)&Sp[(size_t)(b * 8 + tile) * KD + t * 4] = s4;
  }
}

__global__ __launch_bounds__(TPB) void f_makeV(const float* __restrict__ ws,
                                               const float* __restrict__ W,
                                               float* __restrict__ V,
                                               int pass) {
  const int b = blockIdx.x, t = threadIdx.x;
  __shared__ float gsum[JCAP * KD];   // pass0 uses first 128 only
  __shared__ float o_s[JDIM];
  if (pass == 0) {
    const float* Sp = ws + WS_SP + (size_t)b * 8 * KD;
    if (t < KD) {
      float s = 0.f;
#pragma unroll
      for (int tl = 0; tl < 8; ++tl) s += Sp[tl * KD + t];
      gsum[t] = s * 0.1f;
    }
  } else {
    const float* Gp1 = ws + WS_GP1 + (size_t)b * 8 * JCAP * KD;
    for (int i = t; i < JCAP * KD; i += TPB) {
      float s = 0.f;
#pragma unroll
      for (int tl = 0; tl < 8; ++tl) s += Gp1[tl * JCAP * KD + i];
      gsum[i] = s;
    }
  }
  __syncthreads();
  if (t < JDIM) {
    const int j = t >> 4;
    const float* gs = pass == 0 ? gsum : (gsum + j * KD);
    float acc = 0.f;
#pragma unroll 4
    for (int k = 0; k < KD; ++k) acc += gs[k] * W[k * JDIM + t];
    o_s[t] = acc;
  }
  __syncthreads();
  const int k = t & 127, gg = t >> 7;
#pragma unroll
  for (int i = 0; i < 5; ++i) {
    const int j = gg * 5 + i;
    const float* wp = W + k * JDIM + j * DCAP;
    float acc = 0.f;
#pragma unroll
    for (int d = 0; d < DCAP; ++d) acc += wp[d] * o_s[j * DCAP + d];
    V[(size_t)(b * JCAP + j) * KD + k] = acc;
  }
}

__global__ __launch_bounds__(TPB) void f_route(const float* __restrict__ u,
                                               const float* __restrict__ V,
                                               const float* __restrict__ W,
                                               float* __restrict__ dst,
                                               int pass) {
  const int b = blockIdx.y, tile = blockIdx.x, t = threadIdx.x;
  const int r0 = tile * 256;
  __shared__ __align__(16) float Cs[JCAP][260];
  __shared__ __align__(16) float Gp[4][JCAP][KD];
  {
    const float* up = u + (size_t)(b * NN + r0 + t) * KD;
    const float* vb = V + (size_t)(b * JCAP) * KD;
    float acc[JCAP];
#pragma unroll
    for (int j = 0; j < JCAP; ++j) acc[j] = 0.f;
    for (int kc = 0; kc < KD; kc += 8) {
      float4 xa = *(const float4*)(up + kc);
      float4 xb = *(const float4*)(up + kc + 4);
#pragma unroll
      for (int j = 0; j < JCAP; ++j) {
        float4 v0 = *(const float4*)(vb + j * KD + kc);
        float4 v1 = *(const float4*)(vb + j * KD + kc + 4);
        acc[j] += xa.x * v0.x + xa.y * v0.y + xa.z * v0.z + xa.w * v0.w
                + xb.x * v1.x + xb.y * v1.y + xb.z * v1.z + xb.w * v1.w;
      }
    }
    float m = acc[0];
#pragma unroll
    for (int j = 1; j < JCAP; ++j) m = fmaxf(m, acc[j]);
    float s = 0.f;
#pragma unroll
    for (int j = 0; j < JCAP; ++j) { acc[j] = __expf(acc[j] - m); s += acc[j]; }
    const float inv = 1.f / s;
#pragma unroll
    for (int j = 0; j < JCAP; ++j) Cs[j][t] = acc[j] * inv;
  }
  __syncthreads();
  {
    const int wave = t >> 6, lane = t & 63;
    const int rw = wave * 64;
    float g0[JCAP], g1[JCAP];
#pragma unroll
    for (int j = 0; j < JCAP; ++j) { g0[j] = 0.f; g1[j] = 0.f; }
    const float* ub = u + (size_t)(b * NN + r0 + rw) * KD + 2 * lane;
    for (int rc = 0; rc < 64; rc += 4) {
      float ua[4], uc[4];
#pragma unroll
      for (int q = 0; q < 4; ++q) {
        float2 w = *(const float2*)(ub + (size_t)(rc + q) * KD);
        ua[q] = w.x; uc[q] = w.y;
      }
#pragma unroll
      for (int j = 0; j < JCAP; ++j) {
        float4 c4 = *(const float4*)&Cs[j][rw + rc];
        g0[j] += c4.x * ua[0] + c4.y * ua[1] + c4.z * ua[2] + c4.w * ua[3];
        g1[j] += c4.x * uc[0] + c4.y * uc[1] + c4.z * uc[2] + c4.w * uc[3];
      }
    }
#pragma unroll
    for (int j = 0; j < JCAP; ++j)
      *(float2*)&Gp[wave][j][2 * lane] = make_float2(g0[j], g1[j]);
  }
  __syncthreads();
  if (pass == 0) {
    float* Gp1 = dst + (size_t)(b * 8 + tile) * JCAP * KD;
    for (int i = t; i < JCAP * KD; i += TPB)
      Gp1[i] = Gp[0][0][i] + Gp[1][0][i] + Gp[2][0][i] + Gp[3][0][i];
  } else {
    for (int i = t; i < JCAP * KD; i += TPB)
      Gp[0][0][i] = Gp[0][0][i] + Gp[1][0][i] + Gp[2][0][i] + Gp[3][0][i];
    __syncthreads();
    if (t < JDIM) {
      const int j = t >> 4;
      float acc = 0.f;
#pragma unroll 4
      for (int k = 0; k < KD; ++k) acc += Gp[0][j][k] * W[k * JDIM + t];
      dst[(size_t)(b * 8 + tile) * JDIM + t] = acc;
    }
  }
}

__global__ __launch_bounds__(TPB) void f_squash(const float* __restrict__ O2p,
                                                float* __restrict__ out) {
  const int b = blockIdx.x, t = threadIdx.x;
  __shared__ float o_s[JDIM];
  __shared__ float sc[JCAP];
  if (t < JDIM) {
    const float* p = O2p + (size_t)b * 8 * JDIM;
    float s = 0.f;
#pragma unroll
    for (int tl = 0; tl < 8; ++tl) s += p[tl * JDIM + t];
    o_s[t] = s;
  }
  __syncthreads();
  if (t < JCAP) {
    float s2 = 0.f;
#pragma unroll
    for (int d = 0; d < DCAP; ++d) { float x = o_s[t * DCAP + d]; s2 += x * x; }
    sc[t] = s2 / ((1.f + s2) * sqrtf(s2 + EPSQ));
  }
  __syncthreads();
  if (t < JDIM) out[b * JDIM + t] = o_s[t] * sc[t >> 4];
}

extern "C" void kernel_launch(void* const* d_in, const int* in_sizes, int n_in,
                              void* d_out, int out_size, void* d_ws, size_t ws_size,
                              hipStream_t stream) {
  const float* u = (const float*)d_in[0];   // (64,2048,128) fp32
  const float* W = (const float*)d_in[1];   // (128,160) fp32
  float* out = (float*)d_out;               // (64,10,16) fp32
  float* ws  = (float*)d_ws;

  void* args[] = {(void*)&u, (void*)&W, (void*)&out, (void*)&ws};
  hipError_t e = hipLaunchCooperativeKernel((const void*)k_caps, dim3(NBLK),
                                            dim3(TPB), args, 0, stream);
  if (e == hipSuccess) return;

  // deterministic fallback chain (no atomics, no memset)
  float* Sp  = ws + WS_SP;
  float* V   = ws + WS_V;
  float* Gp1 = ws + WS_GP1;
  float* O2p = ws + WS_O2P;
  f_colsum<<<dim3(8, BATCH), TPB, 0, stream>>>(u, Sp);
  f_makeV <<<BATCH, TPB, 0, stream>>>(ws, W, V, 0);
  f_route <<<dim3(8, BATCH), TPB, 0, stream>>>(u, V, W, Gp1, 0);
  f_makeV <<<BATCH, TPB, 0, stream>>>(ws, W, V, 1);
  f_route <<<dim3(8, BATCH), TPB, 0, stream>>>(u, V, W, O2p, 1);
  f_squash<<<BATCH, TPB, 0, stream>>>(O2p, out);
}

// Round 5
// 172.796 us; speedup vs baseline: 2.2075x; 2.2075x over previous
//
#include <hip/hip_runtime.h>
#include <math.h>

// Capsule dynamic routing, MI355X. Round 5: deterministic 6-dispatch chain,
// no atomics, no memset (all reductions via per-tile partial buffers).
//   logits[b,j,n] = u[b,n,:] . V[b,j,:],  V[b,j,k] = sum_d W[k,jd]*o[b,j,d]
//   o[b,j,d]      = sum_k G[b,j,k]*W[k,jd], G[b,j,k] = sum_n c[b,j,n]*u[b,n,k]
// iter0: c uniform 0.1 -> o0 = 0.1*(colsum u)@W.
// V kept in GLOBAL so phase-1's wave-uniform V reads compile to s_loads
// (scalar cache) instead of LDS broadcast traffic (R4 lesson).

#define BATCH 64
#define NN    2048
#define KD    128
#define JCAP  10
#define DCAP  16
#define JDIM  160
#define EPSQ  1e-7f
#define TPB   256

// ws layout (floats): Sp[64][8][128] @0 ; V[64][10][128] @65536 ;
// Gp1[64][8][10][128] @147456 ; O2p[64][8][160] @802816
#define WS_SP   0
#define WS_V    65536
#define WS_GP1  147456
#define WS_O2P  802816

// ---- K1: per-tile column sums Sp[b][tile][k] = sum_{n in tile} u[b][n][k]
__global__ __launch_bounds__(TPB) void f_colsum(const float* __restrict__ u,
                                                float* __restrict__ Sp) {
  const int b = blockIdx.y, tile = blockIdx.x, t = threadIdx.x;
  const int k4 = (t & 31) * 4, rg = t >> 5;
  __shared__ float4 red[256];
  const float* p = u + ((size_t)(b * NN) + tile * 256 + rg * 32) * KD + k4;
  float4 a = make_float4(0.f, 0.f, 0.f, 0.f);
#pragma unroll 4
  for (int r = 0; r < 32; ++r) {
    float4 w = *(const float4*)(p + (size_t)r * KD);
    a.x += w.x; a.y += w.y; a.z += w.z; a.w += w.w;
  }
  red[t] = a;
  __syncthreads();
  if (t < 32) {
    float4 s4 = red[t];
#pragma unroll
    for (int rg2 = 1; rg2 < 8; ++rg2) {
      float4 w = red[rg2 * 32 + t];
      s4.x += w.x; s4.y += w.y; s4.z += w.z; s4.w += w.w;
    }
    *(float4*)&Sp[(size_t)(b * 8 + tile) * KD + t * 4] = s4;
  }
}

// ---- K2/K4: fold partials -> o = Gsum@W -> V[b][j][k] (global) ----
__global__ __launch_bounds__(TPB) void f_makeV(const float* __restrict__ ws,
                                               const float* __restrict__ W,
                                               float* __restrict__ V,
                                               int pass) {
  const int b = blockIdx.x, t = threadIdx.x;
  __shared__ float gsum[JCAP * KD];   // pass0 uses first 128 only
  __shared__ float o_s[JDIM];
  if (pass == 0) {
    const float* Sp = ws + WS_SP + (size_t)b * 8 * KD;
    if (t < KD) {
      float s = 0.f;
#pragma unroll
      for (int tl = 0; tl < 8; ++tl) s += Sp[tl * KD + t];
      gsum[t] = s * 0.1f;
    }
  } else {
    const float* Gp1 = ws + WS_GP1 + (size_t)b * 8 * JCAP * KD;
    for (int i = t; i < JCAP * KD; i += TPB) {
      float s = 0.f;
#pragma unroll
      for (int tl = 0; tl < 8; ++tl) s += Gp1[tl * JCAP * KD + i];
      gsum[i] = s;
    }
  }
  __syncthreads();
  if (t < JDIM) {
    const int j = t >> 4;
    const float* gs = pass == 0 ? gsum : (gsum + j * KD);
    float acc = 0.f;
#pragma unroll 4
    for (int k = 0; k < KD; ++k) acc += gs[k] * W[k * JDIM + t];
    o_s[t] = acc;
  }
  __syncthreads();
  const int k = t & 127, gg = t >> 7;
#pragma unroll
  for (int i = 0; i < 5; ++i) {
    const int j = gg * 5 + i;
    const float* wp = W + k * JDIM + j * DCAP;
    float acc = 0.f;
#pragma unroll
    for (int d = 0; d < DCAP; ++d) acc += wp[d] * o_s[j * DCAP + d];
    V[(size_t)(b * JCAP + j) * KD + k] = acc;
  }
}

// ---- K3/K5: routing pass: logits -> softmax_j -> per-tile G partials ----
// pass0: dst = Gp1 partials [b][tile][10][128]
// pass1: dst = O2p partials [b][tile][160] (G folded through W in-block)
__global__ __launch_bounds__(TPB) void f_route(const float* __restrict__ u,
                                               const float* __restrict__ V,
                                               const float* __restrict__ W,
                                               float* __restrict__ dst,
                                               int pass) {
  const int b = blockIdx.y, tile = blockIdx.x, t = threadIdx.x;
  const int r0 = tile * 256;
  __shared__ __align__(16) float Cs[JCAP][260];
  __shared__ __align__(16) float Gp[4][JCAP][KD];
  // phase 1: thread = row; V reads are wave-uniform -> s_loads
  {
    const float* up = u + (size_t)(b * NN + r0 + t) * KD;
    const float* vb = V + (size_t)(b * JCAP) * KD;
    float acc[JCAP];
#pragma unroll
    for (int j = 0; j < JCAP; ++j) acc[j] = 0.f;
    for (int kc = 0; kc < KD; kc += 8) {
      float4 xa = *(const float4*)(up + kc);
      float4 xb = *(const float4*)(up + kc + 4);
#pragma unroll
      for (int j = 0; j < JCAP; ++j) {
        float4 v0 = *(const float4*)(vb + j * KD + kc);
        float4 v1 = *(const float4*)(vb + j * KD + kc + 4);
        acc[j] += xa.x * v0.x + xa.y * v0.y + xa.z * v0.z + xa.w * v0.w
                + xb.x * v1.x + xb.y * v1.y + xb.z * v1.z + xb.w * v1.w;
      }
    }
    float m = acc[0];
#pragma unroll
    for (int j = 1; j < JCAP; ++j) m = fmaxf(m, acc[j]);
    float s = 0.f;
#pragma unroll
    for (int j = 0; j < JCAP; ++j) { acc[j] = __expf(acc[j] - m); s += acc[j]; }
    const float inv = 1.f / s;
#pragma unroll
    for (int j = 0; j < JCAP; ++j) Cs[j][t] = acc[j] * inv;
  }
  __syncthreads();
  // phase 2: wave = 64 rows, lane = k-pair (coalesced row reads)
  {
    const int wave = t >> 6, lane = t & 63;
    const int rw = wave * 64;
    float g0[JCAP], g1[JCAP];
#pragma unroll
    for (int j = 0; j < JCAP; ++j) { g0[j] = 0.f; g1[j] = 0.f; }
    const float* ub = u + (size_t)(b * NN + r0 + rw) * KD + 2 * lane;
    for (int rc = 0; rc < 64; rc += 4) {
      float ua[4], uc[4];
#pragma unroll
      for (int q = 0; q < 4; ++q) {
        float2 w = *(const float2*)(ub + (size_t)(rc + q) * KD);
        ua[q] = w.x; uc[q] = w.y;
      }
#pragma unroll
      for (int j = 0; j < JCAP; ++j) {
        float4 c4 = *(const float4*)&Cs[j][rw + rc];
        g0[j] += c4.x * ua[0] + c4.y * ua[1] + c4.z * ua[2] + c4.w * ua[3];
        g1[j] += c4.x * uc[0] + c4.y * uc[1] + c4.z * uc[2] + c4.w * uc[3];
      }
    }
#pragma unroll
    for (int j = 0; j < JCAP; ++j)
      *(float2*)&Gp[wave][j][2 * lane] = make_float2(g0[j], g1[j]);
  }
  __syncthreads();
  if (pass == 0) {
    float* Gp1 = dst + (size_t)(b * 8 + tile) * JCAP * KD;
    for (int i = t; i < JCAP * KD; i += TPB)
      Gp1[i] = Gp[0][0][i] + Gp[1][0][i] + Gp[2][0][i] + Gp[3][0][i];
  } else {
    for (int i = t; i < JCAP * KD; i += TPB)
      Gp[0][0][i] = Gp[0][0][i] + Gp[1][0][i] + Gp[2][0][i] + Gp[3][0][i];
    __syncthreads();
    if (t < JDIM) {
      const int j = t >> 4;
      float acc = 0.f;
#pragma unroll 4
      for (int k = 0; k < KD; ++k) acc += Gp[0][j][k] * W[k * JDIM + t];
      dst[(size_t)(b * 8 + tile) * JDIM + t] = acc;
    }
  }
}

// ---- K6: fold O2 partials, squash, store ----
__global__ __launch_bounds__(TPB) void f_squash(const float* __restrict__ O2p,
                                                float* __restrict__ out) {
  const int b = blockIdx.x, t = threadIdx.x;
  __shared__ float o_s[JDIM];
  __shared__ float sc[JCAP];
  if (t < JDIM) {
    const float* p = O2p + (size_t)b * 8 * JDIM;
    float s = 0.f;
#pragma unroll
    for (int tl = 0; tl < 8; ++tl) s += p[tl * JDIM + t];
    o_s[t] = s;
  }
  __syncthreads();
  if (t < JCAP) {
    float s2 = 0.f;
#pragma unroll
    for (int d = 0; d < DCAP; ++d) { float x = o_s[t * DCAP + d]; s2 += x * x; }
    sc[t] = s2 / ((1.f + s2) * sqrtf(s2 + EPSQ));
  }
  __syncthreads();
  if (t < JDIM) out[b * JDIM + t] = o_s[t] * sc[t >> 4];
}

extern "C" void kernel_launch(void* const* d_in, const int* in_sizes, int n_in,
                              void* d_out, int out_size, void* d_ws, size_t ws_size,
                              hipStream_t stream) {
  const float* u = (const float*)d_in[0];   // (64,2048,128) fp32
  const float* W = (const float*)d_in[1];   // (128,160) fp32
  float* out = (float*)d_out;               // (64,10,16) fp32
  float* ws  = (float*)d_ws;

  float* Sp  = ws + WS_SP;
  float* V   = ws + WS_V;
  float* Gp1 = ws + WS_GP1;
  float* O2p = ws + WS_O2P;
  f_colsum<<<dim3(8, BATCH), TPB, 0, stream>>>(u, Sp);
  f_makeV <<<BATCH, TPB, 0, stream>>>(ws, W, V, 0);
  f_route <<<dim3(8, BATCH), TPB, 0, stream>>>(u, V, W, Gp1, 0);
  f_makeV <<<BATCH, TPB, 0, stream>>>(ws, W, V, 1);
  f_route <<<dim3(8, BATCH), TPB, 0, stream>>>(u, V, W, O2p, 1);
  f_squash<<<BATCH, TPB, 0, stream>>>(O2p, out);
}